// Round 1
// baseline (5605.211 us; speedup 1.0000x reference)
//
#include <hip/hip_runtime.h>
#include <math.h>
#include <stdint.h>

// ---- problem constants ----
#define B_      64
#define S_      128
#define H_      768
#define L_      6
#define NH_     12
#define DH_     64
#define FF_     3072
#define INTENT_ 22
#define TAGS_   122
#define NT_     (B_*S_)          // 8192 tokens
#define LN_EPS  1e-12f
#define INV_SQRT_DH 0.125f

#define GF_RELU_OUT 2
#define GF_GELU_OUT 4
#define GF_ADDRES   16   // add residual from Rh/Rl halves
#define GF_ACCH     32   // accumulate from current OH/OL contents

typedef _Float16 half8 __attribute__((ext_vector_type(8)));
typedef float    f32x4 __attribute__((ext_vector_type(4)));

// ===================== async global->LDS 16B =====================
__device__ __forceinline__ void gld16(const _Float16* g, _Float16* l) {
    __builtin_amdgcn_global_load_lds(
        (const __attribute__((address_space(1))) unsigned int*)(uintptr_t)g,
        (__attribute__((address_space(3))) unsigned int*)(unsigned int)(uintptr_t)l,
        16, 0, 0);
}

__device__ inline float wave_max(float v){
    #pragma unroll
    for (int d = 32; d; d >>= 1) v = fmaxf(v, __shfl_xor(v, d));
    return v;
}
__device__ inline float wave_sum(float v){
    #pragma unroll
    for (int d = 32; d; d >>= 1) v += __shfl_xor(v, d);
    return v;
}

// ===================== embedding + LN -> split halves =====================
__global__ __launch_bounds__(256) void embed_ln_kernel(
    const int* __restrict__ ids, const float* __restrict__ we,
    const float* __restrict__ pe, const float* __restrict__ gs,
    const float* __restrict__ gb, _Float16* __restrict__ Xh,
    _Float16* __restrict__ Xl)
{
    __shared__ float red[256];
    int bs = blockIdx.x;
    int sq = bs % S_;
    int id = ids[bs];
    int tid = threadIdx.x;
    const float* wrow = we + (size_t)id * H_;
    const float* prow = pe + (size_t)sq * H_;
    float z[3];
    #pragma unroll
    for (int r = 0; r < 3; r++) {
        int h = tid + 256*r;
        z[r] = wrow[h] + prow[h];
    }
    float sum = z[0]+z[1]+z[2];
    red[tid] = sum; __syncthreads();
    for (int off = 128; off > 0; off >>= 1) {
        if (tid < off) red[tid] += red[tid+off];
        __syncthreads();
    }
    float m = red[0] * (1.0f/H_); __syncthreads();
    float vs = 0.f;
    #pragma unroll
    for (int r = 0; r < 3; r++) { float d = z[r]-m; vs += d*d; }
    red[tid] = vs; __syncthreads();
    for (int off = 128; off > 0; off >>= 1) {
        if (tid < off) red[tid] += red[tid+off];
        __syncthreads();
    }
    float rstd = 1.0f / sqrtf(red[0]*(1.0f/H_) + LN_EPS);
    #pragma unroll
    for (int r = 0; r < 3; r++) {
        int h = tid + 256*r;
        float val = (z[r]-m)*rstd*gs[h] + gb[h];
        _Float16 hv = (_Float16)val;
        Xh[(size_t)bs*H_ + h] = hv;
        Xl[(size_t)bs*H_ + h] = (_Float16)(val - (float)hv);
    }
}

// ===================== LN over sum-halves -> split halves (+relu copy) ====
__global__ __launch_bounds__(384) void ln2_kernel(
    const _Float16* __restrict__ Sh, const _Float16* __restrict__ Sl,
    const float* __restrict__ gs, const float* __restrict__ gb,
    _Float16* __restrict__ Xh, _Float16* __restrict__ Xl,
    _Float16* __restrict__ Rh, _Float16* __restrict__ Rl)
{
    __shared__ float red[512];
    int bs = blockIdx.x, tid = threadIdx.x;
    size_t base = (size_t)bs*H_ + tid*2;
    union UU { _Float16 h[2]; unsigned u; };
    UU uh, ul;
    uh.u = *(const unsigned*)(Sh + base);
    ul.u = *(const unsigned*)(Sl + base);
    float z0 = (float)uh.h[0] + (float)ul.h[0];
    float z1 = (float)uh.h[1] + (float)ul.h[1];
    red[tid] = z0 + z1;
    if (tid < 128) red[384+tid] = 0.f;
    __syncthreads();
    for (int off = 256; off > 0; off >>= 1) {
        if (tid < off) red[tid] += red[tid+off];
        __syncthreads();
    }
    float m = red[0] * (1.0f/H_);
    __syncthreads();
    float d0 = z0-m, d1 = z1-m;
    red[tid] = d0*d0 + d1*d1;
    if (tid < 128) red[384+tid] = 0.f;
    __syncthreads();
    for (int off = 256; off > 0; off >>= 1) {
        if (tid < off) red[tid] += red[tid+off];
        __syncthreads();
    }
    float rstd = 1.0f / sqrtf(red[0]*(1.0f/H_) + LN_EPS);
    float2 gv = *(const float2*)(gs + tid*2);
    float2 bv = *(const float2*)(gb + tid*2);
    float v0 = d0*rstd*gv.x + bv.x;
    float v1 = d1*rstd*gv.y + bv.y;
    UU oh, ol;
    oh.h[0] = (_Float16)v0; ol.h[0] = (_Float16)(v0 - (float)oh.h[0]);
    oh.h[1] = (_Float16)v1; ol.h[1] = (_Float16)(v1 - (float)oh.h[1]);
    *(unsigned*)(Xh + base) = oh.u;
    *(unsigned*)(Xl + base) = ol.u;
    if (Rh) {
        float r0 = fmaxf(v0, 0.f), r1 = fmaxf(v1, 0.f);
        UU rh, rl;
        rh.h[0] = (_Float16)r0; rl.h[0] = (_Float16)(r0 - (float)rh.h[0]);
        rh.h[1] = (_Float16)r1; rl.h[1] = (_Float16)(r1 - (float)rh.h[1]);
        *(unsigned*)(Rh + base) = rh.u;
        *(unsigned*)(Rl + base) = rl.u;
    }
}

// ===================== weight transpose + fp16 hi/lo split =====================
// W [K][N] fp32 row-major -> Wt hi/lo [N][K] halves. grid (K/64, N/64, nz)
__global__ __launch_bounds__(256) void wconv_kernel(
    const float* __restrict__ W0, const float* __restrict__ W1,
    const float* __restrict__ W2, const float* __restrict__ W3,
    int K, int N, _Float16* __restrict__ OH, _Float16* __restrict__ OL, long zoff)
{
    __shared__ float t[64][65];
    int z = blockIdx.z;
    const float* W = (z==0) ? W0 : ((z==1) ? W1 : ((z==2) ? W2 : W3));
    OH += (long)z*zoff; OL += (long)z*zoff;
    int k0 = blockIdx.x*64, n0 = blockIdx.y*64;
    int tid = threadIdx.x;
    int lr = tid>>4, lc = (tid&15)*4;
    #pragma unroll
    for (int p = 0; p < 4; p++) {
        float4 v = *(const float4*)&W[(size_t)(k0+lr+16*p)*N + n0 + lc];
        t[lr+16*p][lc]   = v.x; t[lr+16*p][lc+1] = v.y;
        t[lr+16*p][lc+2] = v.z; t[lr+16*p][lc+3] = v.w;
    }
    __syncthreads();
    int n = tid>>2, kb = (tid&3)*16;
    union U { _Float16 h[8]; uint4 u; } h0, h1, l0, l1;
    #pragma unroll
    for (int e = 0; e < 8; e++) {
        float x = t[kb+e][n];
        _Float16 hv = (_Float16)x;
        h0.h[e] = hv; l0.h[e] = (_Float16)(x - (float)hv);
    }
    #pragma unroll
    for (int e = 0; e < 8; e++) {
        float x = t[kb+8+e][n];
        _Float16 hv = (_Float16)x;
        h1.h[e] = hv; l1.h[e] = (_Float16)(x - (float)hv);
    }
    size_t ob = (size_t)(n0+n)*K + k0 + kb;
    *(uint4*)&OH[ob]   = h0.u;
    *(uint4*)&OH[ob+8] = h1.u;
    *(uint4*)&OL[ob]   = l0.u;
    *(uint4*)&OL[ob+8] = l1.u;
}

// ===================== MFMA fp16-split GEMM v3 (global_load_lds staging) ====
// All inputs pre-split halves. M fixed by grid.x*128, N by grid.y*128, K param.
// LDS layout is FRAGMENT-LINEAR (bank-conflict-free):
//   for 16-row block q, lane l holds global (row = q*16+(l&15), k = (l>>4)*8)
//   at LDS offset q*512 + l*8 halves. Staging achieves this by permuting the
//   per-lane GLOBAL source address (global_load_lds dest is linear, rule #21);
//   the wave's ds_read_b128 of one fragment block is then a contiguous 1KB
//   chunk -> zero LDS bank conflicts (was 8 lanes/bank with row-major [128][32]).
__global__ __launch_bounds__(256) void gemm3_kernel(
    const _Float16* __restrict__ AhG, const _Float16* __restrict__ AlG, int lda,
    const _Float16* __restrict__ WtHb, const _Float16* __restrict__ WtLb,
    int ldw, long wz,
    float* __restrict__ C, _Float16* __restrict__ OHb, _Float16* __restrict__ OLb,
    int ldc, long oz,
    const _Float16* __restrict__ Rh, const _Float16* __restrict__ Rl, int ldr,
    const float* __restrict__ bias0, const float* __restrict__ bias1,
    const float* __restrict__ bias2,
    int K, int flags)
{
    __shared__ __align__(16) _Float16 Ah[128*32], Al[128*32];
    __shared__ __align__(16) _Float16 Bh[128*32], Bl[128*32];
    const int z = blockIdx.z;
    const _Float16* WtH = WtHb + (long)z*wz;
    const _Float16* WtL = WtLb + (long)z*wz;
    _Float16* oh = OHb ? OHb + (long)z*oz : (_Float16*)0;
    _Float16* ol = OLb ? OLb + (long)z*oz : (_Float16*)0;
    const float* bias = (z==0) ? bias0 : ((z==1) ? bias1 : bias2);
    const int tid = threadIdx.x, lane = tid&63, wid = tid>>6;
    const int wm = wid&1, wn = wid>>1;
    const int l15 = lane&15, quad = lane>>4;
    const int m0 = blockIdx.x*128, n0 = blockIdx.y*128;

    // staging assignment: wave 0->Ah, 1->Al, 2->Bh, 3->Bl
    const _Float16* gsrc; _Float16* lbuf; int ld_s; int r0;
    if (wid == 0)      { gsrc = AhG; lbuf = Ah; ld_s = lda; r0 = m0; }
    else if (wid == 1) { gsrc = AlG; lbuf = Al; ld_s = lda; r0 = m0; }
    else if (wid == 2) { gsrc = WtH; lbuf = Bh; ld_s = ldw; r0 = n0; }
    else               { gsrc = WtL; lbuf = Bl; ld_s = ldw; r0 = n0; }
    // fragment-linear source permutation: lane l -> (row l&15, k-chunk l>>4)
    const _Float16* gbase = gsrc + (size_t)(r0 + (lane&15))*ld_s + (lane>>4)*8;

    f32x4 acc[4][4];
    #pragma unroll
    for (int i = 0; i < 4; i++)
        #pragma unroll
        for (int j = 0; j < 4; j++)
            acc[i][j] = (f32x4){0.f,0.f,0.f,0.f};

    for (int k0 = 0; k0 < K; k0 += 32) {
        #pragma unroll
        for (int q = 0; q < 8; q++)
            gld16(gbase + (size_t)(q*16)*ld_s + k0, lbuf + q*512);
        __syncthreads();
        half8 afh[4], afl[4], bfh[4], bfl[4];
        #pragma unroll
        for (int i = 0; i < 4; i++) {
            afh[i] = *(const half8*)&Ah[(wm*4+i)*512 + lane*8];
            afl[i] = *(const half8*)&Al[(wm*4+i)*512 + lane*8];
            bfh[i] = *(const half8*)&Bh[(wn*4+i)*512 + lane*8];
            bfl[i] = *(const half8*)&Bl[(wn*4+i)*512 + lane*8];
        }
        #pragma unroll
        for (int i = 0; i < 4; i++)
            #pragma unroll
            for (int j = 0; j < 4; j++) {
                acc[i][j] = __builtin_amdgcn_mfma_f32_16x16x32_f16(afh[i], bfh[j], acc[i][j], 0,0,0);
                acc[i][j] = __builtin_amdgcn_mfma_f32_16x16x32_f16(afh[i], bfl[j], acc[i][j], 0,0,0);
                acc[i][j] = __builtin_amdgcn_mfma_f32_16x16x32_f16(afl[i], bfh[j], acc[i][j], 0,0,0);
            }
        __syncthreads();
    }
    // ---- epilogue: C/D layout col=lane&15, row=quad*4+reg ----
    #pragma unroll
    for (int i = 0; i < 4; i++)
        #pragma unroll
        for (int j = 0; j < 4; j++)
            #pragma unroll
            for (int r = 0; r < 4; r++) {
                int gm = m0 + wm*64 + i*16 + quad*4 + r;
                int gn = n0 + wn*64 + j*16 + l15;
                float v = acc[i][j][r];
                if (bias) v += bias[gn];
                size_t ox = (size_t)gm*ldc + gn;
                if (flags & GF_ADDRES) {
                    size_t rx = (size_t)gm*ldr + gn;
                    v += (float)Rh[rx] + (float)Rl[rx];
                }
                if (flags & GF_ACCH)
                    v += (float)oh[ox] + (float)ol[ox];
                if (flags & GF_RELU_OUT) v = fmaxf(v, 0.f);
                if (flags & GF_GELU_OUT) v = 0.5f*v*(1.0f + erff(v*0.70710678118654752f));
                if (oh) {
                    _Float16 hv = (_Float16)v;
                    oh[ox] = hv;
                    ol[ox] = (_Float16)(v - (float)hv);
                } else {
                    C[ox] = v;
                }
            }
}

// ===================== fp32 GEMM (small head GEMM, N=122) =====================
#define BM 64
#define BN 64
#define BK 16
__global__ __launch_bounds__(256) void gemm_kernel(
    const float* __restrict__ A, int lda,
    const float* __restrict__ W, int ldb,
    float* __restrict__ C, int ldc,
    const float* __restrict__ bias,
    int M, int N, int K)
{
    __shared__ __align__(16) float As[BK][BM+4];
    __shared__ __align__(16) float Bs[BK][BN+4];
    int tid = threadIdx.x;
    int tx = tid & 15, ty = tid >> 4;
    int m0 = blockIdx.x * BM;
    int n0 = blockIdx.y * BN;
    float acc[4][4] = {};
    for (int k0 = 0; k0 < K; k0 += BK) {
        #pragma unroll
        for (int r = 0; r < 4; r++) {
            int li = tid + 256*r;
            int m  = li >> 4;
            int kk = li & 15;
            int gm = m0 + m, gk = k0 + kk;
            As[kk][m] = (gm < M && gk < K) ? A[(size_t)gm*lda + gk] : 0.f;
        }
        #pragma unroll
        for (int r = 0; r < 4; r++) {
            int li = tid + 256*r;
            int kk = li >> 6;
            int n  = li & 63;
            int gk = k0 + kk, gn = n0 + n;
            Bs[kk][n] = (gk < K && gn < N) ? W[(size_t)gk*ldb + gn] : 0.f;
        }
        __syncthreads();
        #pragma unroll
        for (int kk = 0; kk < BK; kk++) {
            float4 a  = *(const float4*)&As[kk][ty*4];
            float4 bb = *(const float4*)&Bs[kk][tx*4];
            float av[4] = {a.x, a.y, a.z, a.w};
            float bv[4] = {bb.x, bb.y, bb.z, bb.w};
            #pragma unroll
            for (int i = 0; i < 4; i++)
                #pragma unroll
                for (int j = 0; j < 4; j++)
                    acc[i][j] += av[i] * bv[j];
        }
        __syncthreads();
    }
    #pragma unroll
    for (int i = 0; i < 4; i++) {
        int gm = m0 + ty*4 + i;
        if (gm >= M) continue;
        #pragma unroll
        for (int j = 0; j < 4; j++) {
            int gn = n0 + tx*4 + j;
            if (gn >= N) continue;
            float v = acc[i][j];
            if (bias) v += bias[gn];
            C[(size_t)gm*ldc + gn] = v;
        }
    }
}

// ===================== MFMA attention =====================
__device__ inline int scidx(int row, int col) {
    return row*128 + (((col>>2) ^ (row&7))<<2) + (col&3);
}
__global__ __launch_bounds__(256) void attn2_kernel(
    const _Float16* __restrict__ QhG, const _Float16* __restrict__ QlG,
    const _Float16* __restrict__ KhG, const _Float16* __restrict__ KlG,
    const _Float16* __restrict__ VhG, const _Float16* __restrict__ VlG,
    const int* __restrict__ amask,
    _Float16* __restrict__ Ch, _Float16* __restrict__ Cl)
{
    __shared__ __align__(16) char smem[65536];
    _Float16* Qh_s = (_Float16*)smem;            // [64][72]
    _Float16* Ql_s = Qh_s + 64*72;
    _Float16* Kh_s = Ql_s + 64*72;               // [128][72]
    _Float16* Kl_s = Kh_s + 128*72;
    float*    Sc   = (float*)smem;               // [64][128] swizzled (phase 2)
    _Float16* Vth  = (_Float16*)(smem + 32768);  // [64][128] swizzled
    _Float16* Vtl  = Vth + 64*128;

    int blk = blockIdx.x;
    int qh2 = blk & 1;
    int bh  = blk >> 1;
    int b = bh / NH_, hh = bh % NH_;
    const int tid = threadIdx.x, lane = tid&63, wid = tid>>6;
    const int l15 = lane&15, quad = lane>>4;
    const int qr = wid*16;
    size_t tokb = (size_t)b*S_*H_ + (size_t)hh*DH_;

    float nmask[8];
    #pragma unroll
    for (int j = 0; j < 8; j++)
        nmask[j] = (amask[b*S_ + j*16 + l15] > 0) ? 0.f : -1e9f;

    {
        int row = tid>>2, part = (tid&3)*16;
        size_t qg = tokb + (size_t)(qh2*64 + row)*H_ + part;
        *(uint4*)&Qh_s[row*72 + part] = *(const uint4*)(QhG + qg);
        *(uint4*)&Ql_s[row*72 + part] = *(const uint4*)(QlG + qg);
        #pragma unroll
        for (int p = 0; p < 2; p++) {
            int krow = row + p*64;
            size_t kg = tokb + (size_t)krow*H_ + part;
            *(uint4*)&Kh_s[krow*72 + part] = *(const uint4*)(KhG + kg);
            *(uint4*)&Kl_s[krow*72 + part] = *(const uint4*)(KlG + kg);
        }
    }
    __syncthreads();

    f32x4 acc1[8];
    #pragma unroll
    for (int j = 0; j < 8; j++) acc1[j] = (f32x4){0.f,0.f,0.f,0.f};
    half8 aqh[2], aql[2];
    #pragma unroll
    for (int kc = 0; kc < 2; kc++) {
        aqh[kc] = *(const half8*)&Qh_s[(qr + l15)*72 + kc*32 + quad*8];
        aql[kc] = *(const half8*)&Ql_s[(qr + l15)*72 + kc*32 + quad*8];
    }
    #pragma unroll
    for (int j = 0; j < 8; j++) {
        #pragma unroll
        for (int kc = 0; kc < 2; kc++) {
            half8 bkh = *(const half8*)&Kh_s[(j*16 + l15)*72 + kc*32 + quad*8];
            half8 bkl = *(const half8*)&Kl_s[(j*16 + l15)*72 + kc*32 + quad*8];
            acc1[j] = __builtin_amdgcn_mfma_f32_16x16x32_f16(aqh[kc], bkh, acc1[j], 0,0,0);
            acc1[j] = __builtin_amdgcn_mfma_f32_16x16x32_f16(aqh[kc], bkl, acc1[j], 0,0,0);
            acc1[j] = __builtin_amdgcn_mfma_f32_16x16x32_f16(aql[kc], bkh, acc1[j], 0,0,0);
        }
    }
    __syncthreads();

    #pragma unroll
    for (int j = 0; j < 8; j++)
        #pragma unroll
        for (int r = 0; r < 4; r++) {
            int row = qr + quad*4 + r;
            int col = j*16 + l15;
            Sc[scidx(row, col)] = acc1[j][r]*INV_SQRT_DH + nmask[j];
        }
    {
        int key = tid>>1, dh = (tid&1)*32;
        union V32 { _Float16 h[32]; uint4 u[4]; } bufh, bufl;
        #pragma unroll
        for (int e = 0; e < 4; e++) {
            bufh.u[e] = *(const uint4*)(VhG + tokb + (size_t)key*H_ + dh + e*8);
            bufl.u[e] = *(const uint4*)(VlG + tokb + (size_t)key*H_ + dh + e*8);
        }
        int kg = key>>3, kr = key&7;
        #pragma unroll
        for (int e = 0; e < 32; e++) {
            int d = dh + e;
            int pos = kg ^ (d & 7);
            Vth[d*128 + pos*8 + kr] = bufh.h[e];
            Vtl[d*128 + pos*8 + kr] = bufl.h[e];
        }
    }
    __syncthreads();

    {
        int row = tid>>2, part = (tid&3)*32;
        float mx = -INFINITY;
        #pragma unroll 8
        for (int e = 0; e < 32; e++)
            mx = fmaxf(mx, Sc[scidx(row, part+e)]);
        mx = fmaxf(mx, __shfl_xor(mx, 1));
        mx = fmaxf(mx, __shfl_xor(mx, 2));
        float s = 0.f;
        #pragma unroll 8
        for (int e = 0; e < 32; e++) {
            int idx = scidx(row, part+e);
            float ev = expf(Sc[idx] - mx);
            Sc[idx] = ev; s += ev;
        }
        s += __shfl_xor(s, 1);
        s += __shfl_xor(s, 2);
        float inv = 1.0f / s;
        #pragma unroll 8
        for (int e = 0; e < 32; e++)
            Sc[scidx(row, part+e)] *= inv;
    }
    __syncthreads();

    f32x4 acc2[4];
    #pragma unroll
    for (int jd = 0; jd < 4; jd++) acc2[jd] = (f32x4){0.f,0.f,0.f,0.f};
    #pragma unroll
    for (int kc = 0; kc < 4; kc++) {
        int q = qr + l15;
        int g16 = kc*8 + quad*2;
        float4 p0 = *(const float4*)&Sc[q*128 + ((g16   ^ (q&7))<<2)];
        float4 p1 = *(const float4*)&Sc[q*128 + (((g16+1) ^ (q&7))<<2)];
        float pv[8] = {p0.x,p0.y,p0.z,p0.w, p1.x,p1.y,p1.z,p1.w};
        union U { _Float16 h[8]; half8 v; } ph, pl;
        #pragma unroll
        for (int e = 0; e < 8; e++) {
            _Float16 hv = (_Float16)pv[e];
            ph.h[e] = hv; pl.h[e] = (_Float16)(pv[e] - (float)hv);
        }
        #pragma unroll
        for (int jd = 0; jd < 4; jd++) {
            int n = jd*16 + l15;
            int pos = (kc*4 + quad) ^ (n & 7);
            half8 vh = *(const half8*)&Vth[n*128 + pos*8];
            half8 vl = *(const half8*)&Vtl[n*128 + pos*8];
            acc2[jd] = __builtin_amdgcn_mfma_f32_16x16x32_f16(ph.v, vh, acc2[jd], 0,0,0);
            acc2[jd] = __builtin_amdgcn_mfma_f32_16x16x32_f16(ph.v, vl, acc2[jd], 0,0,0);
            acc2[jd] = __builtin_amdgcn_mfma_f32_16x16x32_f16(pl.v, vh, acc2[jd], 0,0,0);
        }
    }
    #pragma unroll
    for (int jd = 0; jd < 4; jd++)
        #pragma unroll
        for (int r = 0; r < 4; r++) {
            int row = qr + quad*4 + r;
            int token = b*S_ + qh2*64 + row;
            int d = jd*16 + l15;
            float v = acc2[jd][r];
            _Float16 hv = (_Float16)v;
            Ch[(size_t)token*H_ + hh*DH_ + d] = hv;
            Cl[(size_t)token*H_ + hh*DH_ + d] = (_Float16)(v - (float)hv);
        }
}

// ===================== intent head =====================
__global__ __launch_bounds__(64) void intent_kernel(
    const _Float16* __restrict__ Xh, const _Float16* __restrict__ Xl,
    const float* __restrict__ iW1,
    const float* __restrict__ ib1, const float* __restrict__ iW2,
    const float* __restrict__ ib2, const int* __restrict__ tgt,
    float* __restrict__ iloss, float* __restrict__ outf)
{
    int b = blockIdx.x; int j = threadIdx.x;
    __shared__ float h1[64];
    __shared__ float lg[32];
    const _Float16* x0h = Xh + (size_t)b*S_*H_;
    const _Float16* x0l = Xl + (size_t)b*S_*H_;
    float acc = ib1[j];
    for (int h = 0; h < H_; h++) {
        float x = (float)x0h[h] + (float)x0l[h];
        acc += fmaxf(x, 0.f) * iW1[(size_t)h*64 + j];
    }
    h1[j] = fmaxf(acc, 0.f);
    __syncthreads();
    if (j < INTENT_) {
        float l = ib2[j];
        for (int k = 0; k < 64; k++) l += h1[k]*iW2[k*INTENT_ + j];
        lg[j] = l;
    }
    __syncthreads();
    if (j == 0) {
        float mx = -INFINITY; int bi = 0;
        for (int c = 0; c < INTENT_; c++) if (lg[c] > mx) { mx = lg[c]; bi = c; }
        float sm = 0.f;
        for (int c = 0; c < INTENT_; c++) sm += expf(lg[c]-mx);
        float lse = mx + logf(sm);
        iloss[b] = lse - lg[tgt[b]];
        outf[1 + (size_t)NT_ + b] = (float)bi;
    }
}

// ===================== fused CRF-llh + Viterbi =====================
// grid (64, 2): y=0 -> CRF llh for batch x ; y=1 -> Viterbi for batch x.
// 512 threads: j = tid>>2 (tag), p = tid&3 (i-partition, i = 4e+p).
#define VST 130
__global__ __launch_bounds__(512) void crf_vit_kernel(
    const float* __restrict__ E_, const int* __restrict__ tags,
    const int* __restrict__ mask, const float* __restrict__ start,
    const float* __restrict__ endv, const float* __restrict__ trans,
    float* __restrict__ crfv, unsigned char* __restrict__ BPg,
    float* __restrict__ outf)
{
    __shared__ __align__(16) float tT[TAGS_*VST];   // [j][i], stride 130
    __shared__ float alpha[TAGS_+2];
    __shared__ float ealpha[TAGS_+2];
    __shared__ float mxbuf[16];
    __shared__ int lastt;
    int b = blockIdx.x;
    int mode = blockIdx.y;
    int tid = threadIdx.x, lane = tid&63, wid = tid>>6;
    int j = tid>>2, p = tid&3;
    int cnt = (p < 2) ? 31 : 30;
    const float* E = E_ + (size_t)b*S_*TAGS_;

    if (j < TAGS_) {
        for (int e = 0; e < cnt; e++) {
            int i = 4*e + p;
            float tv = trans[i*TAGS_ + j];
            tT[j*VST + i] = mode ? tv : expf(tv);
        }
        if (p == 0) alpha[j] = start[j] + E[j];
    }
    __syncthreads();

    if (mode == 0) {
        // ---------- CRF log-likelihood ----------
        for (int t = 1; t < S_; t++) {
            if (wid == 0) {
                float a = (lane < TAGS_) ? alpha[lane] : -3e38f;
                if (lane + 64 < TAGS_) a = fmaxf(a, alpha[lane+64]);
                a = wave_max(a);
                if (lane == 0) mxbuf[0] = a;
            }
            __syncthreads();
            float mx = mxbuf[0];
            if (p == 0 && j < TAGS_) ealpha[j] = expf(alpha[j] - mx);
            __syncthreads();
            float s = 0.f;
            if (j < TAGS_) {
                const float* tr = &tT[j*VST];
                for (int e = 0; e < cnt; e++) {
                    int i = 4*e + p;
                    s += ealpha[i]*tr[i];
                }
            }
            s += __shfl_xor(s, 1);
            s += __shfl_xor(s, 2);
            int m_t = mask[b*S_ + t];
            float ee = (j < TAGS_) ? E[(size_t)t*TAGS_ + j] : 0.f;
            float nv = mx + logf(s) + ee;
            __syncthreads();
            if (p == 0 && j < TAGS_ && m_t) alpha[j] = nv;
            __syncthreads();
        }
        // numerator over timesteps (threads 0..127 handle t)
        float term = 0.f, mkf = 0.f;
        if (tid < S_) {
            int mk = mask[b*S_ + tid]; mkf = (float)mk;
            if (tid >= 1 && mk) {
                int tg = tags[b*S_ + tid], tgp = tags[b*S_ + tid - 1];
                term = trans[tgp*TAGS_ + tg] + E[(size_t)tid*TAGS_ + tg];
            }
        }
        if (wid < 2) {
            float ts = wave_sum(term);
            float ms = wave_sum(mkf);
            if (lane == 0) { mxbuf[2+wid] = ts; mxbuf[4+wid] = ms; }
        }
        __syncthreads();
        if (wid == 0) {
            float v1 = (lane < TAGS_) ? alpha[lane] + endv[lane] : -3e38f;
            float v2 = (lane+64 < TAGS_) ? alpha[lane+64] + endv[lane+64] : -3e38f;
            float m = wave_max(fmaxf(v1, v2));
            float sd = ((lane < TAGS_) ? expf(v1 - m) : 0.f)
                     + ((lane+64 < TAGS_) ? expf(v2 - m) : 0.f);
            sd = wave_sum(sd);
            if (lane == 0) {
                float denom = m + logf(sd);
                float numsum = mxbuf[2] + mxbuf[3];
                int msum = (int)(mxbuf[4] + mxbuf[5]);
                int tag0 = tags[b*S_];
                int last_tag = tags[b*S_ + (msum - 1)];
                float num = start[tag0] + E[tag0] + numsum + endv[last_tag];
                crfv[b] = num - denom;
            }
        }
    } else {
        // ---------- Viterbi ----------
        size_t bpb = (size_t)b*(S_-1)*TAGS_;
        for (int t = 1; t < S_; t++) {
            float best = -3e38f; int bi = 0;
            if (j < TAGS_) {
                const float* tr = &tT[j*VST];
                for (int e = 0; e < cnt; e++) {
                    int i = 4*e + p;
                    float v = alpha[i] + tr[i];
                    if (v > best) { best = v; bi = i; }
                }
            }
            {
                float ov = __shfl_xor(best, 1); int oi = __shfl_xor(bi, 1);
                if (ov > best || (ov == best && oi < bi)) { best = ov; bi = oi; }
                ov = __shfl_xor(best, 2); oi = __shfl_xor(bi, 2);
                if (ov > best || (ov == best && oi < bi)) { best = ov; bi = oi; }
            }
            int m_t = mask[b*S_ + t];
            float ee = (j < TAGS_) ? E[(size_t)t*TAGS_ + j] : 0.f;
            float nv; int nb;
            if (m_t) { nv = best + ee; nb = bi; }
            else     { nv = (j < TAGS_) ? alpha[j] : 0.f; nb = j; }
            __syncthreads();
            if (p == 0 && j < TAGS_) {
                alpha[j] = nv;
                BPg[bpb + (size_t)(t-1)*TAGS_ + j] = (unsigned char)nb;
            }
            __syncthreads();
        }
        if (wid == 0) {
            float v; int idx;
            float v1 = (lane < TAGS_) ? alpha[lane] + endv[lane] : -3e38f;
            float v2 = (lane+64 < TAGS_) ? alpha[lane+64] + endv[lane+64] : -3e38f;
            if (v2 > v1) { v = v2; idx = lane+64; } else { v = v1; idx = lane; }
            #pragma unroll
            for (int d = 32; d; d >>= 1) {
                float ov = __shfl_xor(v, d); int oi = __shfl_xor(idx, d);
                if (ov > v || (ov == v && oi < idx)) { v = ov; idx = oi; }
            }
            if (lane == 0) lastt = idx;
        }
        __syncthreads();
        unsigned char* bpl = (unsigned char*)tT;
        for (int o = tid; o < (S_-1)*TAGS_; o += 512)
            bpl[o] = BPg[bpb + o];
        __syncthreads();
        if (tid == 0) {
            int tag = lastt;
            outf[1 + (size_t)b*S_ + (S_-1)] = (float)tag;
            for (int t = S_-1; t >= 1; t--) {
                tag = bpl[(t-1)*TAGS_ + tag];
                outf[1 + (size_t)b*S_ + (t-1)] = (float)tag;
            }
        }
    }
}

// ===================== final joint loss =====================
__global__ void combine_kernel(const float* __restrict__ iloss,
                               const float* __restrict__ crfv,
                               const float* __restrict__ lv,
                               float* __restrict__ outf)
{
    if (threadIdx.x == 0 && blockIdx.x == 0) {
        float si = 0.f, sc = 0.f;
        for (int b = 0; b < B_; b++) { si += iloss[b]; sc += crfv[b]; }
        float p1 = expf(-lv[0]), p2 = expf(-lv[1]);
        float slots_loss = -sc;
        outf[0] = p1*si + (float)B_*lv[0] + p2*slots_loss + lv[1];
    }
}

// ===================== host launch =====================
extern "C" void kernel_launch(void* const* d_in, const int* in_sizes, int n_in,
                              void* d_out, int out_size, void* d_ws, size_t ws_size,
                              hipStream_t stream) {
    const int*   ids   = (const int*)  d_in[0];
    const int*   amask = (const int*)  d_in[1];
    const int*   itgt  = (const int*)  d_in[2];
    const int*   stgt  = (const int*)  d_in[3];
    const int*   smask = (const int*)  d_in[4];
    const float* we    = (const float*)d_in[5];
    const float* pe    = (const float*)d_in[6];
    const float* embs  = (const float*)d_in[7];
    const float* embb  = (const float*)d_in[8];
    const float* Wq    = (const float*)d_in[9];
    const float* bq    = (const float*)d_in[10];
    const float* Wk    = (const float*)d_in[11];
    const float* bk    = (const float*)d_in[12];
    const float* Wv    = (const float*)d_in[13];
    const float* bv    = (const float*)d_in[14];
    const float* Wo    = (const float*)d_in[15];
    const float* bo    = (const float*)d_in[16];
    const float* sas   = (const float*)d_in[17];
    const float* sab   = (const float*)d_in[18];
    const float* W1f   = (const float*)d_in[19];
    const float* b1f   = (const float*)d_in[20];
    const float* W2f   = (const float*)d_in[21];
    const float* b2f   = (const float*)d_in[22];
    const float* ols   = (const float*)d_in[23];
    const float* olb   = (const float*)d_in[24];
    const float* iW1   = (const float*)d_in[25];
    const float* ib1   = (const float*)d_in[26];
    const float* iW2   = (const float*)d_in[27];
    const float* ib2   = (const float*)d_in[28];
    const float* sW1   = (const float*)d_in[29];
    const float* sb1   = (const float*)d_in[30];
    const float* sW2   = (const float*)d_in[31];
    const float* sb2   = (const float*)d_in[32];
    const float* crfs  = (const float*)d_in[33];
    const float* crfe  = (const float*)d_in[34];
    const float* crft  = (const float*)d_in[35];
    const float* lv    = (const float*)d_in[36];

    float* outf = (float*)d_out;
    float* wsf  = (float*)d_ws;
    const long NTHh = (long)NT_ * H_;        // 6,291,456 (halves per tensor)
    const long NBf  = NTHh;                  // floats per fp32-equivalent tensor
    const long HH   = (long)H_ * H_;         // 589,824

    // layout (floats): [XhXl: NBf][P: 3*NBf][ChCl: NBf][WA][WB1][WB2][misc]
    _Float16* Xh = (_Float16*)wsf;
    _Float16* Xl = Xh + NTHh;
    float*    Pf = wsf + NBf;
    _Float16* Ph = (_Float16*)Pf;
    _Float16 *Qh = Ph, *Ql = Ph + NTHh, *Kh = Ph + 2*NTHh, *Kl = Ph + 3*NTHh,
             *Vh = Ph + 4*NTHh, *Vl = Ph + 5*NTHh;
    _Float16 *Sh = Ph, *Sl = Ph + NTHh;                 // sum halves (reuse Q slot)
    _Float16* Fh = (_Float16*)(wsf + 2*NBf);            // FF intermediate hi
    _Float16* Fl = (_Float16*)(wsf + 3*NBf);            // FF intermediate lo
    _Float16* Ch = (_Float16*)(wsf + 4*NBf);
    _Float16* Cl = Ch + NTHh;
    const long wa0 = 5*NBf;
    _Float16* WAh = (_Float16*)(wsf + wa0);             // 8*HH halves (QKVO hi+lo)
    _Float16* WAl = WAh + 4*HH;
    const long wb1 = wa0 + 2359296;
    _Float16* WB1h = (_Float16*)(wsf + wb1);
    _Float16* WB1l = WB1h + 2359296;
    const long wb2 = wb1 + 2359296;
    _Float16* WB2h = (_Float16*)(wsf + wb2);
    _Float16* WB2l = WB2h + 2359296;
    float* iloss = wsf + wb2 + 2359296;
    float* crfv  = iloss + 64;
    // heads scratch in P region (free after encoder)
    float* H1 = Pf;                                     // 8192*256
    float* logits = Pf + 2097152;                       // 8192*122
    unsigned char* BPg = (unsigned char*)(Pf + 2097152 + 999424);

    auto g3 = [&](int gy, int gz,
                  const _Float16* A_h, const _Float16* A_l, int lda,
                  const _Float16* WtH, const _Float16* WtL, int ldw, long wz,
                  float* C, _Float16* OH, _Float16* OL, int ldc, long oz,
                  const _Float16* Rh, const _Float16* Rl,
                  const float* b0, const float* b1_, const float* b2_,
                  int K, int flags) {
        hipLaunchKernelGGL(gemm3_kernel, dim3(NT_/128, gy, gz), dim3(256), 0, stream,
                           A_h, A_l, lda, WtH, WtL, ldw, wz,
                           C, OH, OL, ldc, oz, Rh, Rl, H_, b0, b1_, b2_, K, flags);
    };

    hipLaunchKernelGGL(embed_ln_kernel, dim3(NT_), dim3(256), 0, stream,
                       ids, we, pe, embs, embb, Xh, Xl);

    for (int i = 0; i < L_; i++) {
        const long WO = (long)i*HH;
        // QKV+O weights -> WA (z=4)
        hipLaunchKernelGGL(wconv_kernel, dim3(12,12,4), dim3(256), 0, stream,
                           Wq+WO, Wk+WO, Wv+WO, Wo+WO, H_, H_, WAh, WAl, HH);
        // QKV (z=3)
        g3(6, 3, Xh, Xl, H_, WAh, WAl, H_, HH,
           nullptr, Ph, Ph+NTHh, H_, 2*NTHh, nullptr, nullptr,
           bq+i*H_, bk+i*H_, bv+i*H_, H_, 0);
        // attention
        hipLaunchKernelGGL(attn2_kernel, dim3(B_*NH_*2), dim3(256), 0, stream,
                           Qh, Ql, Kh, Kl, Vh, Vl, amask, Ch, Cl);
        // O-proj + residual -> sum halves (Sh/Sl)
        g3(6, 1, Ch, Cl, H_, WAh+3*HH, WAl+3*HH, H_, 0,
           nullptr, Sh, Sl, H_, 0, Xh, Xl,
           bo+i*H_, nullptr, nullptr, H_, GF_ADDRES);
        hipLaunchKernelGGL(ln2_kernel, dim3(NT_), dim3(384), 0, stream,
                           Sh, Sl, sas+i*H_, sab+i*H_, Xh, Xl,
                           (_Float16*)nullptr, (_Float16*)nullptr);
        // FF weights
        hipLaunchKernelGGL(wconv_kernel, dim3(12,48,1), dim3(256), 0, stream,
                           W1f+(long)i*H_*FF_, nullptr, nullptr, nullptr,
                           H_, FF_, WB1h, WB1l, 0);
        hipLaunchKernelGGL(wconv_kernel, dim3(48,12,1), dim3(256), 0, stream,
                           W2f+(long)i*FF_*H_, nullptr, nullptr, nullptr,
                           FF_, H_, WB2h, WB2l, 0);
        for (int c = 0; c < 2; c++) {
            const int CW = FF_/2;  // 1536
            g3(12, 1, Xh, Xl, H_,
               WB1h+(long)c*CW*H_, WB1l+(long)c*CW*H_, H_, 0,
               nullptr, Fh, Fl, CW, 0, nullptr, nullptr,
               b1f+(long)i*FF_+c*CW, nullptr, nullptr, H_, GF_GELU_OUT);
            g3(6, 1, Fh, Fl, CW,
               WB2h+(long)c*CW, WB2l+(long)c*CW, FF_, 0,
               nullptr, Sh, Sl, H_, 0, Xh, Xl,
               (c==0) ? (b2f+i*H_) : nullptr, nullptr, nullptr,
               CW, (c==0) ? GF_ADDRES : GF_ACCH);
        }
        hipLaunchKernelGGL(ln2_kernel, dim3(NT_), dim3(384), 0, stream,
                           Sh, Sl, ols+i*H_, olb+i*H_, Xh, Xl,
                           (i==L_-1) ? Ch : (_Float16*)nullptr,
                           (i==L_-1) ? Cl : (_Float16*)nullptr);
    }

    hipLaunchKernelGGL(intent_kernel, dim3(B_), dim3(64), 0, stream,
                       Xh, Xl, iW1, ib1, iW2, ib2, itgt, iloss, outf);

    // slots head: H1 = relu(relu(x)@sW1 + sb1)  (relu(x) halves are in Ch/Cl)
    hipLaunchKernelGGL(wconv_kernel, dim3(12,4,1), dim3(256), 0, stream,
                       sW1, nullptr, nullptr, nullptr, H_, 256,
                       WAh, WAh + (long)256*H_, 0);
    g3(2, 1, Ch, Cl, H_, WAh, WAh + (long)256*H_, H_, 0,
       H1, nullptr, nullptr, 256, 0, nullptr, nullptr,
       sb1, nullptr, nullptr, H_, GF_RELU_OUT);
    hipLaunchKernelGGL(gemm_kernel, dim3(NT_/BM, 2), dim3(256), 0, stream,
                       H1, 256, sW2, TAGS_, logits, TAGS_, sb2, NT_, TAGS_, 256);

    hipLaunchKernelGGL(crf_vit_kernel, dim3(B_, 2), dim3(512), 0, stream,
                       logits, stgt, smask, crfs, crfe, crft, crfv, BPg, outf);

    hipLaunchKernelGGL(combine_kernel, dim3(1), dim3(64), 0, stream,
                       iloss, crfv, lv, outf);
}

// Round 2
// 4869.545 us; speedup vs baseline: 1.1511x; 1.1511x over previous
//
#include <hip/hip_runtime.h>
#include <math.h>
#include <stdint.h>

// ---- problem constants ----
#define B_      64
#define S_      128
#define H_      768
#define L_      6
#define NH_     12
#define DH_     64
#define FF_     3072
#define INTENT_ 22
#define TAGS_   122
#define NT_     (B_*S_)          // 8192 tokens
#define LN_EPS  1e-12f
#define INV_SQRT_DH 0.125f

#define GF_RELU_OUT 2
#define GF_GELU_OUT 4
#define GF_ADDRES   16   // add residual from Rh/Rl halves
#define GF_ACCH     32   // accumulate from current OH/OL contents

typedef _Float16 half8 __attribute__((ext_vector_type(8)));
typedef float    f32x4 __attribute__((ext_vector_type(4)));

// ===================== async global->LDS 16B =====================
__device__ __forceinline__ void gld16(const _Float16* g, _Float16* l) {
    __builtin_amdgcn_global_load_lds(
        (const __attribute__((address_space(1))) unsigned int*)(uintptr_t)g,
        (__attribute__((address_space(3))) unsigned int*)(unsigned int)(uintptr_t)l,
        16, 0, 0);
}

__device__ inline float wave_max(float v){
    #pragma unroll
    for (int d = 32; d; d >>= 1) v = fmaxf(v, __shfl_xor(v, d));
    return v;
}
__device__ inline float wave_sum(float v){
    #pragma unroll
    for (int d = 32; d; d >>= 1) v += __shfl_xor(v, d);
    return v;
}

// ===================== embedding + LN -> split halves =====================
__global__ __launch_bounds__(256) void embed_ln_kernel(
    const int* __restrict__ ids, const float* __restrict__ we,
    const float* __restrict__ pe, const float* __restrict__ gs,
    const float* __restrict__ gb, _Float16* __restrict__ Xh,
    _Float16* __restrict__ Xl)
{
    __shared__ float red[256];
    int bs = blockIdx.x;
    int sq = bs % S_;
    int id = ids[bs];
    int tid = threadIdx.x;
    const float* wrow = we + (size_t)id * H_;
    const float* prow = pe + (size_t)sq * H_;
    float z[3];
    #pragma unroll
    for (int r = 0; r < 3; r++) {
        int h = tid + 256*r;
        z[r] = wrow[h] + prow[h];
    }
    float sum = z[0]+z[1]+z[2];
    red[tid] = sum; __syncthreads();
    for (int off = 128; off > 0; off >>= 1) {
        if (tid < off) red[tid] += red[tid+off];
        __syncthreads();
    }
    float m = red[0] * (1.0f/H_); __syncthreads();
    float vs = 0.f;
    #pragma unroll
    for (int r = 0; r < 3; r++) { float d = z[r]-m; vs += d*d; }
    red[tid] = vs; __syncthreads();
    for (int off = 128; off > 0; off >>= 1) {
        if (tid < off) red[tid] += red[tid+off];
        __syncthreads();
    }
    float rstd = 1.0f / sqrtf(red[0]*(1.0f/H_) + LN_EPS);
    #pragma unroll
    for (int r = 0; r < 3; r++) {
        int h = tid + 256*r;
        float val = (z[r]-m)*rstd*gs[h] + gb[h];
        _Float16 hv = (_Float16)val;
        Xh[(size_t)bs*H_ + h] = hv;
        Xl[(size_t)bs*H_ + h] = (_Float16)(val - (float)hv);
    }
}

// ===================== LN over sum-halves -> split halves (+relu copy) ====
__global__ __launch_bounds__(384) void ln2_kernel(
    const _Float16* __restrict__ Sh, const _Float16* __restrict__ Sl,
    const float* __restrict__ gs, const float* __restrict__ gb,
    _Float16* __restrict__ Xh, _Float16* __restrict__ Xl,
    _Float16* __restrict__ Rh, _Float16* __restrict__ Rl)
{
    __shared__ float red[512];
    int bs = blockIdx.x, tid = threadIdx.x;
    size_t base = (size_t)bs*H_ + tid*2;
    union UU { _Float16 h[2]; unsigned u; };
    UU uh, ul;
    uh.u = *(const unsigned*)(Sh + base);
    ul.u = *(const unsigned*)(Sl + base);
    float z0 = (float)uh.h[0] + (float)ul.h[0];
    float z1 = (float)uh.h[1] + (float)ul.h[1];
    red[tid] = z0 + z1;
    if (tid < 128) red[384+tid] = 0.f;
    __syncthreads();
    for (int off = 256; off > 0; off >>= 1) {
        if (tid < off) red[tid] += red[tid+off];
        __syncthreads();
    }
    float m = red[0] * (1.0f/H_);
    __syncthreads();
    float d0 = z0-m, d1 = z1-m;
    red[tid] = d0*d0 + d1*d1;
    if (tid < 128) red[384+tid] = 0.f;
    __syncthreads();
    for (int off = 256; off > 0; off >>= 1) {
        if (tid < off) red[tid] += red[tid+off];
        __syncthreads();
    }
    float rstd = 1.0f / sqrtf(red[0]*(1.0f/H_) + LN_EPS);
    float2 gv = *(const float2*)(gs + tid*2);
    float2 bv = *(const float2*)(gb + tid*2);
    float v0 = d0*rstd*gv.x + bv.x;
    float v1 = d1*rstd*gv.y + bv.y;
    UU oh, ol;
    oh.h[0] = (_Float16)v0; ol.h[0] = (_Float16)(v0 - (float)oh.h[0]);
    oh.h[1] = (_Float16)v1; ol.h[1] = (_Float16)(v1 - (float)oh.h[1]);
    *(unsigned*)(Xh + base) = oh.u;
    *(unsigned*)(Xl + base) = ol.u;
    if (Rh) {
        float r0 = fmaxf(v0, 0.f), r1 = fmaxf(v1, 0.f);
        UU rh, rl;
        rh.h[0] = (_Float16)r0; rl.h[0] = (_Float16)(r0 - (float)rh.h[0]);
        rh.h[1] = (_Float16)r1; rl.h[1] = (_Float16)(r1 - (float)rh.h[1]);
        *(unsigned*)(Rh + base) = rh.u;
        *(unsigned*)(Rl + base) = rl.u;
    }
}

// ===================== weight transpose + fp16 hi/lo split =====================
// W [K][N] fp32 row-major -> Wt hi/lo [N][K] halves. grid (K/64, N/64, nz)
__global__ __launch_bounds__(256) void wconv_kernel(
    const float* __restrict__ W0, const float* __restrict__ W1,
    const float* __restrict__ W2, const float* __restrict__ W3,
    int K, int N, _Float16* __restrict__ OH, _Float16* __restrict__ OL, long zoff)
{
    __shared__ float t[64][65];
    int z = blockIdx.z;
    const float* W = (z==0) ? W0 : ((z==1) ? W1 : ((z==2) ? W2 : W3));
    OH += (long)z*zoff; OL += (long)z*zoff;
    int k0 = blockIdx.x*64, n0 = blockIdx.y*64;
    int tid = threadIdx.x;
    int lr = tid>>4, lc = (tid&15)*4;
    #pragma unroll
    for (int p = 0; p < 4; p++) {
        float4 v = *(const float4*)&W[(size_t)(k0+lr+16*p)*N + n0 + lc];
        t[lr+16*p][lc]   = v.x; t[lr+16*p][lc+1] = v.y;
        t[lr+16*p][lc+2] = v.z; t[lr+16*p][lc+3] = v.w;
    }
    __syncthreads();
    int n = tid>>2, kb = (tid&3)*16;
    union U { _Float16 h[8]; uint4 u; } h0, h1, l0, l1;
    #pragma unroll
    for (int e = 0; e < 8; e++) {
        float x = t[kb+e][n];
        _Float16 hv = (_Float16)x;
        h0.h[e] = hv; l0.h[e] = (_Float16)(x - (float)hv);
    }
    #pragma unroll
    for (int e = 0; e < 8; e++) {
        float x = t[kb+8+e][n];
        _Float16 hv = (_Float16)x;
        h1.h[e] = hv; l1.h[e] = (_Float16)(x - (float)hv);
    }
    size_t ob = (size_t)(n0+n)*K + k0 + kb;
    *(uint4*)&OH[ob]   = h0.u;
    *(uint4*)&OH[ob+8] = h1.u;
    *(uint4*)&OL[ob]   = l0.u;
    *(uint4*)&OL[ob+8] = l1.u;
}

// ===================== MFMA fp16-split GEMM v3 (global_load_lds staging) ====
// All inputs pre-split halves. M fixed by grid.x*128, N by grid.y*128, K param.
// Staging keeps the COALESCED global pattern (4 consecutive lanes cover one
// contiguous 64B row segment) but XOR-permutes the 16B k-chunk WITHIN each
// row: slot = kchunk ^ ((row>>1)&3). global_load_lds writes LDS linearly
// (rule #21), so the LDS layout inherits the permutation; the fragment
// ds_read_b128 applies the same XOR and lands 2 lanes/bank (free) instead of
// the 8-way conflict of the plain row-major [128][32] layout.
__global__ __launch_bounds__(256) void gemm3_kernel(
    const _Float16* __restrict__ AhG, const _Float16* __restrict__ AlG, int lda,
    const _Float16* __restrict__ WtHb, const _Float16* __restrict__ WtLb,
    int ldw, long wz,
    float* __restrict__ C, _Float16* __restrict__ OHb, _Float16* __restrict__ OLb,
    int ldc, long oz,
    const _Float16* __restrict__ Rh, const _Float16* __restrict__ Rl, int ldr,
    const float* __restrict__ bias0, const float* __restrict__ bias1,
    const float* __restrict__ bias2,
    int K, int flags)
{
    __shared__ __align__(16) _Float16 Ah[128*32], Al[128*32];
    __shared__ __align__(16) _Float16 Bh[128*32], Bl[128*32];
    const int z = blockIdx.z;
    const _Float16* WtH = WtHb + (long)z*wz;
    const _Float16* WtL = WtLb + (long)z*wz;
    _Float16* oh = OHb ? OHb + (long)z*oz : (_Float16*)0;
    _Float16* ol = OLb ? OLb + (long)z*oz : (_Float16*)0;
    const float* bias = (z==0) ? bias0 : ((z==1) ? bias1 : bias2);
    const int tid = threadIdx.x, lane = tid&63, wid = tid>>6;
    const int wm = wid&1, wn = wid>>1;
    const int l15 = lane&15, quad = lane>>4;
    const int m0 = blockIdx.x*128, n0 = blockIdx.y*128;

    // staging assignment: wave 0->Ah, 1->Al, 2->Bh, 3->Bl
    const _Float16* gsrc; _Float16* lbuf; int ld_s; int r0;
    if (wid == 0)      { gsrc = AhG; lbuf = Ah; ld_s = lda; r0 = m0; }
    else if (wid == 1) { gsrc = AlG; lbuf = Al; ld_s = lda; r0 = m0; }
    else if (wid == 2) { gsrc = WtH; lbuf = Bh; ld_s = ldw; r0 = n0; }
    else               { gsrc = WtL; lbuf = Bl; ld_s = ldw; r0 = n0; }
    // coalesced rows (lane>>2) with per-row k-chunk XOR swizzle.
    // swizzle value ((row>>1)&3) is invariant under row += 16*q.
    const int kch = (lane&3) ^ ((lane>>3)&3);
    const _Float16* gbase = gsrc + (size_t)(r0 + (lane>>2))*ld_s + kch*8;

    // fragment-read slot: want k-chunk = quad at row m (m&15 == l15);
    // stored slot = quad ^ ((m>>1)&3) = quad ^ ((l15>>1)&3) for all i-blocks.
    const int slot = quad ^ ((l15>>1)&3);

    f32x4 acc[4][4];
    #pragma unroll
    for (int i = 0; i < 4; i++)
        #pragma unroll
        for (int j = 0; j < 4; j++)
            acc[i][j] = (f32x4){0.f,0.f,0.f,0.f};

    for (int k0 = 0; k0 < K; k0 += 32) {
        #pragma unroll
        for (int q = 0; q < 8; q++)
            gld16(gbase + (size_t)(q*16)*ld_s + k0, lbuf + q*512);
        __syncthreads();
        half8 afh[4], afl[4], bfh[4], bfl[4];
        #pragma unroll
        for (int i = 0; i < 4; i++) {
            int m = wm*64 + i*16 + l15;
            afh[i] = *(const half8*)&Ah[m*32 + slot*8];
            afl[i] = *(const half8*)&Al[m*32 + slot*8];
            int n = wn*64 + i*16 + l15;
            bfh[i] = *(const half8*)&Bh[n*32 + slot*8];
            bfl[i] = *(const half8*)&Bl[n*32 + slot*8];
        }
        #pragma unroll
        for (int i = 0; i < 4; i++)
            #pragma unroll
            for (int j = 0; j < 4; j++) {
                acc[i][j] = __builtin_amdgcn_mfma_f32_16x16x32_f16(afh[i], bfh[j], acc[i][j], 0,0,0);
                acc[i][j] = __builtin_amdgcn_mfma_f32_16x16x32_f16(afh[i], bfl[j], acc[i][j], 0,0,0);
                acc[i][j] = __builtin_amdgcn_mfma_f32_16x16x32_f16(afl[i], bfh[j], acc[i][j], 0,0,0);
            }
        __syncthreads();
    }
    // ---- epilogue: C/D layout col=lane&15, row=quad*4+reg ----
    #pragma unroll
    for (int i = 0; i < 4; i++)
        #pragma unroll
        for (int j = 0; j < 4; j++)
            #pragma unroll
            for (int r = 0; r < 4; r++) {
                int gm = m0 + wm*64 + i*16 + quad*4 + r;
                int gn = n0 + wn*64 + j*16 + l15;
                float v = acc[i][j][r];
                if (bias) v += bias[gn];
                size_t ox = (size_t)gm*ldc + gn;
                if (flags & GF_ADDRES) {
                    size_t rx = (size_t)gm*ldr + gn;
                    v += (float)Rh[rx] + (float)Rl[rx];
                }
                if (flags & GF_ACCH)
                    v += (float)oh[ox] + (float)ol[ox];
                if (flags & GF_RELU_OUT) v = fmaxf(v, 0.f);
                if (flags & GF_GELU_OUT) v = 0.5f*v*(1.0f + erff(v*0.70710678118654752f));
                if (oh) {
                    _Float16 hv = (_Float16)v;
                    oh[ox] = hv;
                    ol[ox] = (_Float16)(v - (float)hv);
                } else {
                    C[ox] = v;
                }
            }
}

// ===================== fp32 GEMM (small head GEMM, N=122) =====================
#define BM 64
#define BN 64
#define BK 16
__global__ __launch_bounds__(256) void gemm_kernel(
    const float* __restrict__ A, int lda,
    const float* __restrict__ W, int ldb,
    float* __restrict__ C, int ldc,
    const float* __restrict__ bias,
    int M, int N, int K)
{
    __shared__ __align__(16) float As[BK][BM+4];
    __shared__ __align__(16) float Bs[BK][BN+4];
    int tid = threadIdx.x;
    int tx = tid & 15, ty = tid >> 4;
    int m0 = blockIdx.x * BM;
    int n0 = blockIdx.y * BN;
    float acc[4][4] = {};
    for (int k0 = 0; k0 < K; k0 += BK) {
        #pragma unroll
        for (int r = 0; r < 4; r++) {
            int li = tid + 256*r;
            int m  = li >> 4;
            int kk = li & 15;
            int gm = m0 + m, gk = k0 + kk;
            As[kk][m] = (gm < M && gk < K) ? A[(size_t)gm*lda + gk] : 0.f;
        }
        #pragma unroll
        for (int r = 0; r < 4; r++) {
            int li = tid + 256*r;
            int kk = li >> 6;
            int n  = li & 63;
            int gk = k0 + kk, gn = n0 + n;
            Bs[kk][n] = (gk < K && gn < N) ? W[(size_t)gk*ldb + gn] : 0.f;
        }
        __syncthreads();
        #pragma unroll
        for (int kk = 0; kk < BK; kk++) {
            float4 a  = *(const float4*)&As[kk][ty*4];
            float4 bb = *(const float4*)&Bs[kk][tx*4];
            float av[4] = {a.x, a.y, a.z, a.w};
            float bv[4] = {bb.x, bb.y, bb.z, bb.w};
            #pragma unroll
            for (int i = 0; i < 4; i++)
                #pragma unroll
                for (int j = 0; j < 4; j++)
                    acc[i][j] += av[i] * bv[j];
        }
        __syncthreads();
    }
    #pragma unroll
    for (int i = 0; i < 4; i++) {
        int gm = m0 + ty*4 + i;
        if (gm >= M) continue;
        #pragma unroll
        for (int j = 0; j < 4; j++) {
            int gn = n0 + tx*4 + j;
            if (gn >= N) continue;
            float v = acc[i][j];
            if (bias) v += bias[gn];
            C[(size_t)gm*ldc + gn] = v;
        }
    }
}

// ===================== MFMA attention =====================
__device__ inline int scidx(int row, int col) {
    return row*128 + (((col>>2) ^ (row&7))<<2) + (col&3);
}
__global__ __launch_bounds__(256) void attn2_kernel(
    const _Float16* __restrict__ QhG, const _Float16* __restrict__ QlG,
    const _Float16* __restrict__ KhG, const _Float16* __restrict__ KlG,
    const _Float16* __restrict__ VhG, const _Float16* __restrict__ VlG,
    const int* __restrict__ amask,
    _Float16* __restrict__ Ch, _Float16* __restrict__ Cl)
{
    __shared__ __align__(16) char smem[65536];
    _Float16* Qh_s = (_Float16*)smem;            // [64][72]
    _Float16* Ql_s = Qh_s + 64*72;
    _Float16* Kh_s = Ql_s + 64*72;               // [128][72]
    _Float16* Kl_s = Kh_s + 128*72;
    float*    Sc   = (float*)smem;               // [64][128] swizzled (phase 2)
    _Float16* Vth  = (_Float16*)(smem + 32768);  // [64][128] swizzled
    _Float16* Vtl  = Vth + 64*128;

    int blk = blockIdx.x;
    int qh2 = blk & 1;
    int bh  = blk >> 1;
    int b = bh / NH_, hh = bh % NH_;
    const int tid = threadIdx.x, lane = tid&63, wid = tid>>6;
    const int l15 = lane&15, quad = lane>>4;
    const int qr = wid*16;
    size_t tokb = (size_t)b*S_*H_ + (size_t)hh*DH_;

    float nmask[8];
    #pragma unroll
    for (int j = 0; j < 8; j++)
        nmask[j] = (amask[b*S_ + j*16 + l15] > 0) ? 0.f : -1e9f;

    {
        int row = tid>>2, part = (tid&3)*16;
        size_t qg = tokb + (size_t)(qh2*64 + row)*H_ + part;
        *(uint4*)&Qh_s[row*72 + part] = *(const uint4*)(QhG + qg);
        *(uint4*)&Ql_s[row*72 + part] = *(const uint4*)(QlG + qg);
        #pragma unroll
        for (int p = 0; p < 2; p++) {
            int krow = row + p*64;
            size_t kg = tokb + (size_t)krow*H_ + part;
            *(uint4*)&Kh_s[krow*72 + part] = *(const uint4*)(KhG + kg);
            *(uint4*)&Kl_s[krow*72 + part] = *(const uint4*)(KlG + kg);
        }
    }
    __syncthreads();

    f32x4 acc1[8];
    #pragma unroll
    for (int j = 0; j < 8; j++) acc1[j] = (f32x4){0.f,0.f,0.f,0.f};
    half8 aqh[2], aql[2];
    #pragma unroll
    for (int kc = 0; kc < 2; kc++) {
        aqh[kc] = *(const half8*)&Qh_s[(qr + l15)*72 + kc*32 + quad*8];
        aql[kc] = *(const half8*)&Ql_s[(qr + l15)*72 + kc*32 + quad*8];
    }
    #pragma unroll
    for (int j = 0; j < 8; j++) {
        #pragma unroll
        for (int kc = 0; kc < 2; kc++) {
            half8 bkh = *(const half8*)&Kh_s[(j*16 + l15)*72 + kc*32 + quad*8];
            half8 bkl = *(const half8*)&Kl_s[(j*16 + l15)*72 + kc*32 + quad*8];
            acc1[j] = __builtin_amdgcn_mfma_f32_16x16x32_f16(aqh[kc], bkh, acc1[j], 0,0,0);
            acc1[j] = __builtin_amdgcn_mfma_f32_16x16x32_f16(aqh[kc], bkl, acc1[j], 0,0,0);
            acc1[j] = __builtin_amdgcn_mfma_f32_16x16x32_f16(aql[kc], bkh, acc1[j], 0,0,0);
        }
    }
    __syncthreads();

    #pragma unroll
    for (int j = 0; j < 8; j++)
        #pragma unroll
        for (int r = 0; r < 4; r++) {
            int row = qr + quad*4 + r;
            int col = j*16 + l15;
            Sc[scidx(row, col)] = acc1[j][r]*INV_SQRT_DH + nmask[j];
        }
    {
        int key = tid>>1, dh = (tid&1)*32;
        union V32 { _Float16 h[32]; uint4 u[4]; } bufh, bufl;
        #pragma unroll
        for (int e = 0; e < 4; e++) {
            bufh.u[e] = *(const uint4*)(VhG + tokb + (size_t)key*H_ + dh + e*8);
            bufl.u[e] = *(const uint4*)(VlG + tokb + (size_t)key*H_ + dh + e*8);
        }
        int kg = key>>3, kr = key&7;
        #pragma unroll
        for (int e = 0; e < 32; e++) {
            int d = dh + e;
            int pos = kg ^ (d & 7);
            Vth[d*128 + pos*8 + kr] = bufh.h[e];
            Vtl[d*128 + pos*8 + kr] = bufl.h[e];
        }
    }
    __syncthreads();

    {
        int row = tid>>2, part = (tid&3)*32;
        float mx = -INFINITY;
        #pragma unroll 8
        for (int e = 0; e < 32; e++)
            mx = fmaxf(mx, Sc[scidx(row, part+e)]);
        mx = fmaxf(mx, __shfl_xor(mx, 1));
        mx = fmaxf(mx, __shfl_xor(mx, 2));
        float s = 0.f;
        #pragma unroll 8
        for (int e = 0; e < 32; e++) {
            int idx = scidx(row, part+e);
            float ev = expf(Sc[idx] - mx);
            Sc[idx] = ev; s += ev;
        }
        s += __shfl_xor(s, 1);
        s += __shfl_xor(s, 2);
        float inv = 1.0f / s;
        #pragma unroll 8
        for (int e = 0; e < 32; e++)
            Sc[scidx(row, part+e)] *= inv;
    }
    __syncthreads();

    f32x4 acc2[4];
    #pragma unroll
    for (int jd = 0; jd < 4; jd++) acc2[jd] = (f32x4){0.f,0.f,0.f,0.f};
    #pragma unroll
    for (int kc = 0; kc < 4; kc++) {
        int q = qr + l15;
        int g16 = kc*8 + quad*2;
        float4 p0 = *(const float4*)&Sc[q*128 + ((g16   ^ (q&7))<<2)];
        float4 p1 = *(const float4*)&Sc[q*128 + (((g16+1) ^ (q&7))<<2)];
        float pv[8] = {p0.x,p0.y,p0.z,p0.w, p1.x,p1.y,p1.z,p1.w};
        union U { _Float16 h[8]; half8 v; } ph, pl;
        #pragma unroll
        for (int e = 0; e < 8; e++) {
            _Float16 hv = (_Float16)pv[e];
            ph.h[e] = hv; pl.h[e] = (_Float16)(pv[e] - (float)hv);
        }
        #pragma unroll
        for (int jd = 0; jd < 4; jd++) {
            int n = jd*16 + l15;
            int pos = (kc*4 + quad) ^ (n & 7);
            half8 vh = *(const half8*)&Vth[n*128 + pos*8];
            half8 vl = *(const half8*)&Vtl[n*128 + pos*8];
            acc2[jd] = __builtin_amdgcn_mfma_f32_16x16x32_f16(ph.v, vh, acc2[jd], 0,0,0);
            acc2[jd] = __builtin_amdgcn_mfma_f32_16x16x32_f16(ph.v, vl, acc2[jd], 0,0,0);
            acc2[jd] = __builtin_amdgcn_mfma_f32_16x16x32_f16(pl.v, vh, acc2[jd], 0,0,0);
        }
    }
    #pragma unroll
    for (int jd = 0; jd < 4; jd++)
        #pragma unroll
        for (int r = 0; r < 4; r++) {
            int row = qr + quad*4 + r;
            int token = b*S_ + qh2*64 + row;
            int d = jd*16 + l15;
            float v = acc2[jd][r];
            _Float16 hv = (_Float16)v;
            Ch[(size_t)token*H_ + hh*DH_ + d] = hv;
            Cl[(size_t)token*H_ + hh*DH_ + d] = (_Float16)(v - (float)hv);
        }
}

// ===================== intent head =====================
__global__ __launch_bounds__(64) void intent_kernel(
    const _Float16* __restrict__ Xh, const _Float16* __restrict__ Xl,
    const float* __restrict__ iW1,
    const float* __restrict__ ib1, const float* __restrict__ iW2,
    const float* __restrict__ ib2, const int* __restrict__ tgt,
    float* __restrict__ iloss, float* __restrict__ outf)
{
    int b = blockIdx.x; int j = threadIdx.x;
    __shared__ float h1[64];
    __shared__ float lg[32];
    const _Float16* x0h = Xh + (size_t)b*S_*H_;
    const _Float16* x0l = Xl + (size_t)b*S_*H_;
    float acc = ib1[j];
    for (int h = 0; h < H_; h++) {
        float x = (float)x0h[h] + (float)x0l[h];
        acc += fmaxf(x, 0.f) * iW1[(size_t)h*64 + j];
    }
    h1[j] = fmaxf(acc, 0.f);
    __syncthreads();
    if (j < INTENT_) {
        float l = ib2[j];
        for (int k = 0; k < 64; k++) l += h1[k]*iW2[k*INTENT_ + j];
        lg[j] = l;
    }
    __syncthreads();
    if (j == 0) {
        float mx = -INFINITY; int bi = 0;
        for (int c = 0; c < INTENT_; c++) if (lg[c] > mx) { mx = lg[c]; bi = c; }
        float sm = 0.f;
        for (int c = 0; c < INTENT_; c++) sm += expf(lg[c]-mx);
        float lse = mx + logf(sm);
        iloss[b] = lse - lg[tgt[b]];
        outf[1 + (size_t)NT_ + b] = (float)bi;
    }
}

// ===================== fused CRF-llh + Viterbi =====================
// grid (64, 2): y=0 -> CRF llh for batch x ; y=1 -> Viterbi for batch x.
// 512 threads: j = tid>>2 (tag), p = tid&3 (i-partition, i = 4e+p).
#define VST 130
__global__ __launch_bounds__(512) void crf_vit_kernel(
    const float* __restrict__ E_, const int* __restrict__ tags,
    const int* __restrict__ mask, const float* __restrict__ start,
    const float* __restrict__ endv, const float* __restrict__ trans,
    float* __restrict__ crfv, unsigned char* __restrict__ BPg,
    float* __restrict__ outf)
{
    __shared__ __align__(16) float tT[TAGS_*VST];   // [j][i], stride 130
    __shared__ float alpha[TAGS_+2];
    __shared__ float ealpha[TAGS_+2];
    __shared__ float mxbuf[16];
    __shared__ int lastt;
    int b = blockIdx.x;
    int mode = blockIdx.y;
    int tid = threadIdx.x, lane = tid&63, wid = tid>>6;
    int j = tid>>2, p = tid&3;
    int cnt = (p < 2) ? 31 : 30;
    const float* E = E_ + (size_t)b*S_*TAGS_;

    if (j < TAGS_) {
        for (int e = 0; e < cnt; e++) {
            int i = 4*e + p;
            float tv = trans[i*TAGS_ + j];
            tT[j*VST + i] = mode ? tv : expf(tv);
        }
        if (p == 0) alpha[j] = start[j] + E[j];
    }
    __syncthreads();

    if (mode == 0) {
        // ---------- CRF log-likelihood ----------
        for (int t = 1; t < S_; t++) {
            if (wid == 0) {
                float a = (lane < TAGS_) ? alpha[lane] : -3e38f;
                if (lane + 64 < TAGS_) a = fmaxf(a, alpha[lane+64]);
                a = wave_max(a);
                if (lane == 0) mxbuf[0] = a;
            }
            __syncthreads();
            float mx = mxbuf[0];
            if (p == 0 && j < TAGS_) ealpha[j] = expf(alpha[j] - mx);
            __syncthreads();
            float s = 0.f;
            if (j < TAGS_) {
                const float* tr = &tT[j*VST];
                for (int e = 0; e < cnt; e++) {
                    int i = 4*e + p;
                    s += ealpha[i]*tr[i];
                }
            }
            s += __shfl_xor(s, 1);
            s += __shfl_xor(s, 2);
            int m_t = mask[b*S_ + t];
            float ee = (j < TAGS_) ? E[(size_t)t*TAGS_ + j] : 0.f;
            float nv = mx + logf(s) + ee;
            __syncthreads();
            if (p == 0 && j < TAGS_ && m_t) alpha[j] = nv;
            __syncthreads();
        }
        // numerator over timesteps (threads 0..127 handle t)
        float term = 0.f, mkf = 0.f;
        if (tid < S_) {
            int mk = mask[b*S_ + tid]; mkf = (float)mk;
            if (tid >= 1 && mk) {
                int tg = tags[b*S_ + tid], tgp = tags[b*S_ + tid - 1];
                term = trans[tgp*TAGS_ + tg] + E[(size_t)tid*TAGS_ + tg];
            }
        }
        if (wid < 2) {
            float ts = wave_sum(term);
            float ms = wave_sum(mkf);
            if (lane == 0) { mxbuf[2+wid] = ts; mxbuf[4+wid] = ms; }
        }
        __syncthreads();
        if (wid == 0) {
            float v1 = (lane < TAGS_) ? alpha[lane] + endv[lane] : -3e38f;
            float v2 = (lane+64 < TAGS_) ? alpha[lane+64] + endv[lane+64] : -3e38f;
            float m = wave_max(fmaxf(v1, v2));
            float sd = ((lane < TAGS_) ? expf(v1 - m) : 0.f)
                     + ((lane+64 < TAGS_) ? expf(v2 - m) : 0.f);
            sd = wave_sum(sd);
            if (lane == 0) {
                float denom = m + logf(sd);
                float numsum = mxbuf[2] + mxbuf[3];
                int msum = (int)(mxbuf[4] + mxbuf[5]);
                int tag0 = tags[b*S_];
                int last_tag = tags[b*S_ + (msum - 1)];
                float num = start[tag0] + E[tag0] + numsum + endv[last_tag];
                crfv[b] = num - denom;
            }
        }
    } else {
        // ---------- Viterbi ----------
        size_t bpb = (size_t)b*(S_-1)*TAGS_;
        for (int t = 1; t < S_; t++) {
            float best = -3e38f; int bi = 0;
            if (j < TAGS_) {
                const float* tr = &tT[j*VST];
                for (int e = 0; e < cnt; e++) {
                    int i = 4*e + p;
                    float v = alpha[i] + tr[i];
                    if (v > best) { best = v; bi = i; }
                }
            }
            {
                float ov = __shfl_xor(best, 1); int oi = __shfl_xor(bi, 1);
                if (ov > best || (ov == best && oi < bi)) { best = ov; bi = oi; }
                ov = __shfl_xor(best, 2); oi = __shfl_xor(bi, 2);
                if (ov > best || (ov == best && oi < bi)) { best = ov; bi = oi; }
            }
            int m_t = mask[b*S_ + t];
            float ee = (j < TAGS_) ? E[(size_t)t*TAGS_ + j] : 0.f;
            float nv; int nb;
            if (m_t) { nv = best + ee; nb = bi; }
            else     { nv = (j < TAGS_) ? alpha[j] : 0.f; nb = j; }
            __syncthreads();
            if (p == 0 && j < TAGS_) {
                alpha[j] = nv;
                BPg[bpb + (size_t)(t-1)*TAGS_ + j] = (unsigned char)nb;
            }
            __syncthreads();
        }
        if (wid == 0) {
            float v; int idx;
            float v1 = (lane < TAGS_) ? alpha[lane] + endv[lane] : -3e38f;
            float v2 = (lane+64 < TAGS_) ? alpha[lane+64] + endv[lane+64] : -3e38f;
            if (v2 > v1) { v = v2; idx = lane+64; } else { v = v1; idx = lane; }
            #pragma unroll
            for (int d = 32; d; d >>= 1) {
                float ov = __shfl_xor(v, d); int oi = __shfl_xor(idx, d);
                if (ov > v || (ov == v && oi < idx)) { v = ov; idx = oi; }
            }
            if (lane == 0) lastt = idx;
        }
        __syncthreads();
        unsigned char* bpl = (unsigned char*)tT;
        for (int o = tid; o < (S_-1)*TAGS_; o += 512)
            bpl[o] = BPg[bpb + o];
        __syncthreads();
        if (tid == 0) {
            int tag = lastt;
            outf[1 + (size_t)b*S_ + (S_-1)] = (float)tag;
            for (int t = S_-1; t >= 1; t--) {
                tag = bpl[(t-1)*TAGS_ + tag];
                outf[1 + (size_t)b*S_ + (t-1)] = (float)tag;
            }
        }
    }
}

// ===================== final joint loss =====================
__global__ void combine_kernel(const float* __restrict__ iloss,
                               const float* __restrict__ crfv,
                               const float* __restrict__ lv,
                               float* __restrict__ outf)
{
    if (threadIdx.x == 0 && blockIdx.x == 0) {
        float si = 0.f, sc = 0.f;
        for (int b = 0; b < B_; b++) { si += iloss[b]; sc += crfv[b]; }
        float p1 = expf(-lv[0]), p2 = expf(-lv[1]);
        float slots_loss = -sc;
        outf[0] = p1*si + (float)B_*lv[0] + p2*slots_loss + lv[1];
    }
}

// ===================== host launch =====================
extern "C" void kernel_launch(void* const* d_in, const int* in_sizes, int n_in,
                              void* d_out, int out_size, void* d_ws, size_t ws_size,
                              hipStream_t stream) {
    const int*   ids   = (const int*)  d_in[0];
    const int*   amask = (const int*)  d_in[1];
    const int*   itgt  = (const int*)  d_in[2];
    const int*   stgt  = (const int*)  d_in[3];
    const int*   smask = (const int*)  d_in[4];
    const float* we    = (const float*)d_in[5];
    const float* pe    = (const float*)d_in[6];
    const float* embs  = (const float*)d_in[7];
    const float* embb  = (const float*)d_in[8];
    const float* Wq    = (const float*)d_in[9];
    const float* bq    = (const float*)d_in[10];
    const float* Wk    = (const float*)d_in[11];
    const float* bk    = (const float*)d_in[12];
    const float* Wv    = (const float*)d_in[13];
    const float* bv    = (const float*)d_in[14];
    const float* Wo    = (const float*)d_in[15];
    const float* bo    = (const float*)d_in[16];
    const float* sas   = (const float*)d_in[17];
    const float* sab   = (const float*)d_in[18];
    const float* W1f   = (const float*)d_in[19];
    const float* b1f   = (const float*)d_in[20];
    const float* W2f   = (const float*)d_in[21];
    const float* b2f   = (const float*)d_in[22];
    const float* ols   = (const float*)d_in[23];
    const float* olb   = (const float*)d_in[24];
    const float* iW1   = (const float*)d_in[25];
    const float* ib1   = (const float*)d_in[26];
    const float* iW2   = (const float*)d_in[27];
    const float* ib2   = (const float*)d_in[28];
    const float* sW1   = (const float*)d_in[29];
    const float* sb1   = (const float*)d_in[30];
    const float* sW2   = (const float*)d_in[31];
    const float* sb2   = (const float*)d_in[32];
    const float* crfs  = (const float*)d_in[33];
    const float* crfe  = (const float*)d_in[34];
    const float* crft  = (const float*)d_in[35];
    const float* lv    = (const float*)d_in[36];

    float* outf = (float*)d_out;
    float* wsf  = (float*)d_ws;
    const long NTHh = (long)NT_ * H_;        // 6,291,456 (halves per tensor)
    const long NBf  = NTHh;                  // floats per fp32-equivalent tensor
    const long HH   = (long)H_ * H_;         // 589,824

    // layout (floats): [XhXl: NBf][P: 3*NBf][ChCl: NBf][WA][WB1][WB2][misc]
    _Float16* Xh = (_Float16*)wsf;
    _Float16* Xl = Xh + NTHh;
    float*    Pf = wsf + NBf;
    _Float16* Ph = (_Float16*)Pf;
    _Float16 *Qh = Ph, *Ql = Ph + NTHh, *Kh = Ph + 2*NTHh, *Kl = Ph + 3*NTHh,
             *Vh = Ph + 4*NTHh, *Vl = Ph + 5*NTHh;
    _Float16 *Sh = Ph, *Sl = Ph + NTHh;                 // sum halves (reuse Q slot)
    _Float16* Fh = (_Float16*)(wsf + 2*NBf);            // FF intermediate hi
    _Float16* Fl = (_Float16*)(wsf + 3*NBf);            // FF intermediate lo
    _Float16* Ch = (_Float16*)(wsf + 4*NBf);
    _Float16* Cl = Ch + NTHh;
    const long wa0 = 5*NBf;
    _Float16* WAh = (_Float16*)(wsf + wa0);             // 8*HH halves (QKVO hi+lo)
    _Float16* WAl = WAh + 4*HH;
    const long wb1 = wa0 + 2359296;
    _Float16* WB1h = (_Float16*)(wsf + wb1);
    _Float16* WB1l = WB1h + 2359296;
    const long wb2 = wb1 + 2359296;
    _Float16* WB2h = (_Float16*)(wsf + wb2);
    _Float16* WB2l = WB2h + 2359296;
    float* iloss = wsf + wb2 + 2359296;
    float* crfv  = iloss + 64;
    // heads scratch in P region (free after encoder)
    float* H1 = Pf;                                     // 8192*256
    float* logits = Pf + 2097152;                       // 8192*122
    unsigned char* BPg = (unsigned char*)(Pf + 2097152 + 999424);

    auto g3 = [&](int gy, int gz,
                  const _Float16* A_h, const _Float16* A_l, int lda,
                  const _Float16* WtH, const _Float16* WtL, int ldw, long wz,
                  float* C, _Float16* OH, _Float16* OL, int ldc, long oz,
                  const _Float16* Rh, const _Float16* Rl,
                  const float* b0, const float* b1_, const float* b2_,
                  int K, int flags) {
        hipLaunchKernelGGL(gemm3_kernel, dim3(NT_/128, gy, gz), dim3(256), 0, stream,
                           A_h, A_l, lda, WtH, WtL, ldw, wz,
                           C, OH, OL, ldc, oz, Rh, Rl, H_, b0, b1_, b2_, K, flags);
    };

    hipLaunchKernelGGL(embed_ln_kernel, dim3(NT_), dim3(256), 0, stream,
                       ids, we, pe, embs, embb, Xh, Xl);

    for (int i = 0; i < L_; i++) {
        const long WO = (long)i*HH;
        // QKV+O weights -> WA (z=4)
        hipLaunchKernelGGL(wconv_kernel, dim3(12,12,4), dim3(256), 0, stream,
                           Wq+WO, Wk+WO, Wv+WO, Wo+WO, H_, H_, WAh, WAl, HH);
        // QKV (z=3)
        g3(6, 3, Xh, Xl, H_, WAh, WAl, H_, HH,
           nullptr, Ph, Ph+NTHh, H_, 2*NTHh, nullptr, nullptr,
           bq+i*H_, bk+i*H_, bv+i*H_, H_, 0);
        // attention
        hipLaunchKernelGGL(attn2_kernel, dim3(B_*NH_*2), dim3(256), 0, stream,
                           Qh, Ql, Kh, Kl, Vh, Vl, amask, Ch, Cl);
        // O-proj + residual -> sum halves (Sh/Sl)
        g3(6, 1, Ch, Cl, H_, WAh+3*HH, WAl+3*HH, H_, 0,
           nullptr, Sh, Sl, H_, 0, Xh, Xl,
           bo+i*H_, nullptr, nullptr, H_, GF_ADDRES);
        hipLaunchKernelGGL(ln2_kernel, dim3(NT_), dim3(384), 0, stream,
                           Sh, Sl, sas+i*H_, sab+i*H_, Xh, Xl,
                           (_Float16*)nullptr, (_Float16*)nullptr);
        // FF weights
        hipLaunchKernelGGL(wconv_kernel, dim3(12,48,1), dim3(256), 0, stream,
                           W1f+(long)i*H_*FF_, nullptr, nullptr, nullptr,
                           H_, FF_, WB1h, WB1l, 0);
        hipLaunchKernelGGL(wconv_kernel, dim3(48,12,1), dim3(256), 0, stream,
                           W2f+(long)i*FF_*H_, nullptr, nullptr, nullptr,
                           FF_, H_, WB2h, WB2l, 0);
        for (int c = 0; c < 2; c++) {
            const int CW = FF_/2;  // 1536
            g3(12, 1, Xh, Xl, H_,
               WB1h+(long)c*CW*H_, WB1l+(long)c*CW*H_, H_, 0,
               nullptr, Fh, Fl, CW, 0, nullptr, nullptr,
               b1f+(long)i*FF_+c*CW, nullptr, nullptr, H_, GF_GELU_OUT);
            g3(6, 1, Fh, Fl, CW,
               WB2h+(long)c*CW, WB2l+(long)c*CW, FF_, 0,
               nullptr, Sh, Sl, H_, 0, Xh, Xl,
               (c==0) ? (b2f+i*H_) : nullptr, nullptr, nullptr,
               CW, (c==0) ? GF_ADDRES : GF_ACCH);
        }
        hipLaunchKernelGGL(ln2_kernel, dim3(NT_), dim3(384), 0, stream,
                           Sh, Sl, ols+i*H_, olb+i*H_, Xh, Xl,
                           (i==L_-1) ? Ch : (_Float16*)nullptr,
                           (i==L_-1) ? Cl : (_Float16*)nullptr);
    }

    hipLaunchKernelGGL(intent_kernel, dim3(B_), dim3(64), 0, stream,
                       Xh, Xl, iW1, ib1, iW2, ib2, itgt, iloss, outf);

    // slots head: H1 = relu(relu(x)@sW1 + sb1)  (relu(x) halves are in Ch/Cl)
    hipLaunchKernelGGL(wconv_kernel, dim3(12,4,1), dim3(256), 0, stream,
                       sW1, nullptr, nullptr, nullptr, H_, 256,
                       WAh, WAh + (long)256*H_, 0);
    g3(2, 1, Ch, Cl, H_, WAh, WAh + (long)256*H_, H_, 0,
       H1, nullptr, nullptr, 256, 0, nullptr, nullptr,
       sb1, nullptr, nullptr, H_, GF_RELU_OUT);
    hipLaunchKernelGGL(gemm_kernel, dim3(NT_/BM, 2), dim3(256), 0, stream,
                       H1, 256, sW2, TAGS_, logits, TAGS_, sb2, NT_, TAGS_, 256);

    hipLaunchKernelGGL(crf_vit_kernel, dim3(B_, 2), dim3(512), 0, stream,
                       logits, stgt, smask, crfs, crfe, crft, crfv, BPg, outf);

    hipLaunchKernelGGL(combine_kernel, dim3(1), dim3(64), 0, stream,
                       iloss, crfv, lv, outf);
}